// Round 6
// baseline (426.474 us; speedup 1.0000x reference)
//
#include <hip/hip_runtime.h>
#include <stdint.h>

#define V_ 50257
#define D_ 1024
#define F_ 2048
#define B_ 64
#define E_ 512
#define ROWS_ (B_*E_)

typedef __attribute__((ext_vector_type(8))) short bf16x8;
typedef __attribute__((ext_vector_type(4))) float f32x4;

__device__ __forceinline__ unsigned rne1(float a) {
  unsigned u = __float_as_uint(a);
  return (u + 0x7FFFu + ((u >> 16) & 1u)) >> 16;
}

__device__ __forceinline__ float waveMax(float v) {
#pragma unroll
  for (int o = 32; o > 0; o >>= 1) v = fmaxf(v, __shfl_xor(v, o, 64));
  return v;
}
__device__ __forceinline__ float waveSum(float v) {
#pragma unroll
  for (int o = 32; o > 0; o >>= 1) v += __shfl_xor(v, o, 64);
  return v;
}

// ---------------- device bodies ----------------

__device__ __forceinline__ void ent_partial_body(int bid, const float* __restrict__ eh,
                                                 const void* __restrict__ mask,
                                                 float* __restrict__ part) {
  __shared__ int s_mode;
  const int tid = threadIdx.x;
  const uint32_t* mu = (const uint32_t*)mask;
  int f = 0;
  for (int i = tid; i < (ROWS_ / 4); i += 256) {
    uint32_t u = mu[i];
    if (u == 0x3F800000u) f |= 2;
    else if (u & 0xFFFFFF00u) f |= 1;
  }
  if (tid == 0) s_mode = 0;
  __syncthreads();
  if (f) atomicOr(&s_mode, f);
  __syncthreads();
  const int sm = s_mode;
  const int mode = (sm & 1) ? 1 : ((sm & 2) ? 2 : 0);

  float4 acc = make_float4(0.f, 0.f, 0.f, 0.f);
  const float4* eh4 = (const float4*)eh;
  for (int row = bid; row < ROWS_; row += 512) {
    bool on;
    if (mode == 1)      on = ((const unsigned char*)mask)[row] != 0;
    else if (mode == 2) on = ((const float*)mask)[row] != 0.f;
    else                on = ((const int*)mask)[row] != 0;
    if (on) {
      float4 v = eh4[(size_t)row * (D_ / 4) + tid];
      acc.x += v.x; acc.y += v.y; acc.z += v.z; acc.w += v.w;
    }
  }
  ((float4*)part)[(size_t)bid * (D_ / 4) + tid] = acc;
}

__device__ __forceinline__ void ent_reduce_body(int bid, const float* __restrict__ part,
                                                float* __restrict__ entsum) {
  int d = bid * 256 + threadIdx.x;
  float s0 = 0.f, s1 = 0.f, s2 = 0.f, s3 = 0.f;
  for (int i = 0; i < 512; i += 4) {
    s0 += part[(size_t)(i    ) * D_ + d];
    s1 += part[(size_t)(i + 1) * D_ + d];
    s2 += part[(size_t)(i + 2) * D_ + d];
    s3 += part[(size_t)(i + 3) * D_ + d];
  }
  entsum[d] = (s0 + s1) + (s2 + s3);
}

__device__ __forceinline__ void gemm64_body(int bx, int by, const float* __restrict__ X,
                                            const int* __restrict__ gatherIdx,
                                            const float* __restrict__ emb,
                                            const float* __restrict__ W,
                                            int K, int N, int KB, float* __restrict__ part) {
  const int l  = threadIdx.x & 63;
  const int rg = __builtin_amdgcn_readfirstlane((int)(threadIdx.x >> 6));
  const int c  = bx * 64 + l;
  const int k0 = by * KB;
  const int m0 = rg * 16;

  const float* Xp = gatherIdx ? emb : X;
  int rb[16];
#pragma unroll
  for (int r = 0; r < 16; ++r) {
    int m = m0 + r;
    rb[r] = gatherIdx ? gatherIdx[m] * K : m * K;
  }

  float acc[16];
#pragma unroll
  for (int r = 0; r < 16; ++r) acc[r] = 0.f;

  for (int k = k0; k < k0 + KB; k += 8) {
    float wv[8];
#pragma unroll
    for (int j = 0; j < 8; ++j) wv[j] = W[(size_t)(k + j) * N + c];
#pragma unroll
    for (int r = 0; r < 16; ++r) {
      float4 x0 = *(const float4*)&Xp[rb[r] + k];
      float4 x1 = *(const float4*)&Xp[rb[r] + k + 4];
      acc[r] = fmaf(x0.x, wv[0], acc[r]);
      acc[r] = fmaf(x0.y, wv[1], acc[r]);
      acc[r] = fmaf(x0.z, wv[2], acc[r]);
      acc[r] = fmaf(x0.w, wv[3], acc[r]);
      acc[r] = fmaf(x1.x, wv[4], acc[r]);
      acc[r] = fmaf(x1.y, wv[5], acc[r]);
      acc[r] = fmaf(x1.z, wv[6], acc[r]);
      acc[r] = fmaf(x1.w, wv[7], acc[r]);
    }
  }
  size_t base = (size_t)by * ((size_t)64 * N);
#pragma unroll
  for (int r = 0; r < 16; ++r) part[base + (size_t)(m0 + r) * N + c] = acc[r];
}

__device__ __forceinline__ void reduce_ep_body(int bid, const float* __restrict__ part,
                                               int nsplit, int MN, int N,
                                               const float* __restrict__ vecB,
                                               const float* __restrict__ addend,
                                               int mode, float* __restrict__ dst,
                                               unsigned short* __restrict__ dhi,
                                               unsigned short* __restrict__ dlo) {
  int idx = bid * 256 + threadIdx.x;
  if (idx >= MN) return;
  float s = 0.f;
  for (int i = 0; i < nsplit; ++i) s += part[(size_t)i * MN + idx];
  int c = idx & (N - 1);
  if (mode == 1)      { s += vecB[c]; s = s > 0.f ? s : 0.f; dst[idx] = s; }
  else if (mode == 2) { s += vecB[c]; dst[idx] = s; }
  else if (mode == 3) { s *= vecB[c]; dst[idx] = s; }
  else {
    s += addend[idx];
    unsigned hi = rne1(s);
    float hif = __uint_as_float(hi << 16);
    dhi[idx] = (unsigned short)hi;
    dlo[idx] = (unsigned short)rne1(s - hif);
  }
}

// ---------------- fused phase kernels ----------------
__global__ void k_p1(const float* __restrict__ eh, const void* __restrict__ mask,
                     float* __restrict__ entpart, const int* __restrict__ ques,
                     const float* __restrict__ emb, const float* __restrict__ W1,
                     float* __restrict__ gpart) {
  int bid = blockIdx.x;
  if (bid < 512) ent_partial_body(bid, eh, mask, entpart);
  else {
    int b2 = bid - 512;
    gemm64_body(b2 & 31, b2 >> 5, nullptr, ques, emb, W1, 1024, 2048, 64, gpart);
  }
}

__global__ void k_p2(const float* __restrict__ entpart, float* __restrict__ entsum,
                     const float* __restrict__ gpart, const float* __restrict__ b1,
                     float* __restrict__ hbuf) {
  int bid = blockIdx.x;
  if (bid < 4) ent_reduce_body(bid, entpart, entsum);
  else reduce_ep_body(bid - 4, gpart, 16, 64 * 2048, 2048, b1, nullptr, 1, hbuf, nullptr, nullptr);
}

__global__ void k_gemm64(const float* __restrict__ X, const float* __restrict__ W,
                         int K, int N, int KB, float* __restrict__ part) {
  gemm64_body(blockIdx.x, blockIdx.y, X, nullptr, nullptr, W, K, N, KB, part);
}

__global__ void k_reduce_ep(const float* __restrict__ part, int nsplit, int MN, int N,
                            const float* __restrict__ vecB, const float* __restrict__ addend,
                            int mode, float* __restrict__ dst,
                            unsigned short* __restrict__ dhi, unsigned short* __restrict__ dlo) {
  reduce_ep_body(blockIdx.x, part, nsplit, MN, N, vecB, addend, mode, dst, dhi, dlo);
}

// ---------------- big GEMM: logits = Z[64,1024] @ Ws[1024,V] + bs, split-bf16 MFMA -------
// 4 waves/block; wave w owns 16 cols, all 64 rows, full K. 2x-unrolled k-loop with named
// A/B buffer sets for BOTH streams (z frags + Ws batch). Compute-X depends only on X-bufs
// issued one full phase earlier -> compiler's own waitcnt is vmcnt(16): the other phase's
// 16 loads stay in flight across every compute phase (counted-vmcnt via dependency shape).
__global__ __launch_bounds__(256, 4) void k_gemm_big(const unsigned short* __restrict__ zhi,
                                                     const unsigned short* __restrict__ zlo,
                                                     const float* __restrict__ Ws,
                                                     const float* __restrict__ bs,
                                                     float* __restrict__ logits) {
  const int l   = threadIdx.x & 63;
  const int w   = threadIdx.x >> 6;
  const int col = l & 15;
  const int g   = l >> 4;            // k-chunk g*8..g*8+7
  const int c   = blockIdx.x * 64 + w * 16 + col;
  const int cc  = c < V_ ? c : V_ - 1;

  unsigned woff[8];
#pragma unroll
  for (int j = 0; j < 8; ++j) woff[j] = (unsigned)((g * 8 + j) * V_ + cc);
  unsigned aoff[4];
#pragma unroll
  for (int m = 0; m < 4; ++m) aoff[m] = (unsigned)((m * 16 + col) * D_ + g * 8);

  f32x4 zero = {0.f, 0.f, 0.f, 0.f};
  f32x4 acc[4];
#pragma unroll
  for (int m = 0; m < 4; ++m) acc[m] = zero;

  bf16x8 ahA[4], alA[4], ahB[4], alB[4];
  float fA[8], fB[8];

  // prologue: phase-A data for k0=0 (z first, then Ws)
#pragma unroll
  for (int m = 0; m < 4; ++m) {
    ahA[m] = *(const bf16x8*)(zhi + aoff[m]);
    alA[m] = *(const bf16x8*)(zlo + aoff[m]);
  }
#pragma unroll
  for (int j = 0; j < 8; ++j) fA[j] = Ws[woff[j]];
#pragma unroll
  for (int j = 0; j < 8; ++j) fB[j] = 0.f;

  for (int k0 = 0; k0 < D_; k0 += 64) {
    // issue phase-B loads (k0+32): z first, then Ws
    {
      const unsigned short* zh = zhi + k0 + 32;
      const unsigned short* zl = zlo + k0 + 32;
#pragma unroll
      for (int m = 0; m < 4; ++m) {
        ahB[m] = *(const bf16x8*)(zh + aoff[m]);
        alB[m] = *(const bf16x8*)(zl + aoff[m]);
      }
      const float* wn = Ws + (size_t)(k0 + 32) * V_;
#pragma unroll
      for (int j = 0; j < 8; ++j) fB[j] = wn[woff[j]];
    }

    // compute phase A (k0)
    {
      union { bf16x8 v; unsigned u[4]; } bh, bl;
#pragma unroll
      for (int j = 0; j < 4; ++j) {
        unsigned h0 = rne1(fA[2 * j]);
        unsigned h1 = rne1(fA[2 * j + 1]);
        float h0f = __uint_as_float(h0 << 16);
        float h1f = __uint_as_float(h1 << 16);
        bh.u[j] = h0 | (h1 << 16);
        bl.u[j] = rne1(fA[2 * j] - h0f) | (rne1(fA[2 * j + 1] - h1f) << 16);
      }
#pragma unroll
      for (int m = 0; m < 4; ++m) acc[m] = __builtin_amdgcn_mfma_f32_16x16x32_bf16(ahA[m], bh.v, acc[m], 0, 0, 0);
#pragma unroll
      for (int m = 0; m < 4; ++m) acc[m] = __builtin_amdgcn_mfma_f32_16x16x32_bf16(ahA[m], bl.v, acc[m], 0, 0, 0);
#pragma unroll
      for (int m = 0; m < 4; ++m) acc[m] = __builtin_amdgcn_mfma_f32_16x16x32_bf16(alA[m], bh.v, acc[m], 0, 0, 0);
    }

    // issue phase-A loads (k0+64): z first, then Ws
    if (k0 + 64 < D_) {
      const unsigned short* zh = zhi + k0 + 64;
      const unsigned short* zl = zlo + k0 + 64;
#pragma unroll
      for (int m = 0; m < 4; ++m) {
        ahA[m] = *(const bf16x8*)(zh + aoff[m]);
        alA[m] = *(const bf16x8*)(zl + aoff[m]);
      }
      const float* wn = Ws + (size_t)(k0 + 64) * V_;
#pragma unroll
      for (int j = 0; j < 8; ++j) fA[j] = wn[woff[j]];
    }

    // compute phase B (k0+32)
    {
      union { bf16x8 v; unsigned u[4]; } bh, bl;
#pragma unroll
      for (int j = 0; j < 4; ++j) {
        unsigned h0 = rne1(fB[2 * j]);
        unsigned h1 = rne1(fB[2 * j + 1]);
        float h0f = __uint_as_float(h0 << 16);
        float h1f = __uint_as_float(h1 << 16);
        bh.u[j] = h0 | (h1 << 16);
        bl.u[j] = rne1(fB[2 * j] - h0f) | (rne1(fB[2 * j + 1] - h1f) << 16);
      }
#pragma unroll
      for (int m = 0; m < 4; ++m) acc[m] = __builtin_amdgcn_mfma_f32_16x16x32_bf16(ahB[m], bh.v, acc[m], 0, 0, 0);
#pragma unroll
      for (int m = 0; m < 4; ++m) acc[m] = __builtin_amdgcn_mfma_f32_16x16x32_bf16(ahB[m], bl.v, acc[m], 0, 0, 0);
#pragma unroll
      for (int m = 0; m < 4; ++m) acc[m] = __builtin_amdgcn_mfma_f32_16x16x32_bf16(alB[m], bh.v, acc[m], 0, 0, 0);
    }
  }

  if (c < V_) {
    float bias = bs[c];
#pragma unroll
    for (int m = 0; m < 4; ++m) {
#pragma unroll
      for (int i = 0; i < 4; ++i)
        logits[(size_t)(m * 16 + g * 4 + i) * V_ + c] = acc[m][i] + bias;
    }
  }
}

// ---------------- softmax over rows of logits [64, V], two-pass 256-block ----------------
#define SM_CHUNK 12565  // 4 * 12565 >= V_

__global__ void k_softmax1(const float* __restrict__ logits, float2* __restrict__ stats) {
  __shared__ float smx[4], ssum[4];
  const int r = blockIdx.x >> 2, q = blockIdx.x & 3;
  const int beg = q * SM_CHUNK;
  const int end = (beg + SM_CHUNK < V_) ? beg + SM_CHUNK : V_;
  const float* row = logits + (size_t)r * V_;

  float mx = -3.4e38f;
  for (int i = beg + threadIdx.x; i < end; i += 256) mx = fmaxf(mx, row[i]);
  mx = waveMax(mx);
  if ((threadIdx.x & 63) == 0) smx[threadIdx.x >> 6] = mx;
  __syncthreads();
  mx = fmaxf(fmaxf(smx[0], smx[1]), fmaxf(smx[2], smx[3]));

  float s = 0.f;
  for (int i = beg + threadIdx.x; i < end; i += 256) s += __expf(row[i] - mx);
  s = waveSum(s);
  if ((threadIdx.x & 63) == 0) ssum[threadIdx.x >> 6] = s;
  __syncthreads();
  s = (ssum[0] + ssum[1]) + (ssum[2] + ssum[3]);

  if (threadIdx.x == 0) stats[blockIdx.x] = make_float2(mx, s);
}

__global__ void k_softmax2(const float* __restrict__ logits, const float2* __restrict__ stats,
                           float* __restrict__ out) {
  const int r = blockIdx.x >> 2, q = blockIdx.x & 3;
  float2 s0 = stats[r * 4 + 0], s1 = stats[r * 4 + 1];
  float2 s2 = stats[r * 4 + 2], s3 = stats[r * 4 + 3];
  float M = fmaxf(fmaxf(s0.x, s1.x), fmaxf(s2.x, s3.x));
  float S = s0.y * __expf(s0.x - M) + s1.y * __expf(s1.x - M)
          + s2.y * __expf(s2.x - M) + s3.y * __expf(s3.x - M);
  float inv = 1.f / S;
  const int beg = q * SM_CHUNK;
  const int end = (beg + SM_CHUNK < V_) ? beg + SM_CHUNK : V_;
  const float* row = logits + (size_t)r * V_;
  float* orow = out + (size_t)r * V_;
  for (int i = beg + threadIdx.x; i < end; i += 256) orow[i] = __expf(row[i] - M) * inv;
}

// ---------------- launch ----------------
extern "C" void kernel_launch(void* const* d_in, const int* in_sizes, int n_in,
                              void* d_out, int out_size, void* d_ws, size_t ws_size,
                              hipStream_t stream) {
  const float* eh   = (const float*)d_in[0];
  const int*   ques = (const int*)d_in[1];
  const void*  mask = d_in[2];
  const float* emb  = (const float*)d_in[3];
  const float* W1   = (const float*)d_in[4];
  const float* b1   = (const float*)d_in[5];
  const float* W2   = (const float*)d_in[6];
  const float* b2   = (const float*)d_in[7];
  const float* A    = (const float*)d_in[8];
  const float* H    = (const float*)d_in[9];
  const float* Ws   = (const float*)d_in[10];
  const float* bs   = (const float*)d_in[11];
  float* out = (float*)d_out;
  char* ws = (char*)d_ws;

  // ws layout (bytes). gpart aliases logits (temporally disjoint).
  float*          logits  = (float*)(ws + 0);           // 64*50257*4 = 12,865,792
  float*          gpart   = (float*)(ws + 0);           // max 8,388,608 (aliased)
  float*          entpart = (float*)(ws + 12866048);    // 2,097,152
  float*          entsum  = (float*)(ws + 14963200);    // 4,096
  float*          hbuf    = (float*)(ws + 14967296);    // 524,288
  float*          qbuf    = (float*)(ws + 15491584);    // 262,144
  float*          ubuf    = (float*)(ws + 15753728);    // 262,144
  unsigned short* zhi16   = (unsigned short*)(ws + 16015872);  // 131,072
  unsigned short* zlo16   = (unsigned short*)(ws + 16146944);  // 131,072
  float2*         stats   = (float2*)(ws + 16278016);   // 2,048

  // P1: ent_partial (512 blocks) || h-gemm partials (512 blocks)
  k_p1<<<1024, 256, 0, stream>>>(eh, mask, entpart, ques, emb, W1, gpart);
  // P2: ent_reduce (4) || h = relu(.+b1) (512)
  k_p2<<<516, 256, 0, stream>>>(entpart, entsum, gpart, b1, hbuf);

  // P3/P4: q = h @ W2 + b2                 [64,1024], K=2048, split 32
  k_gemm64<<<dim3(16, 32), 256, 0, stream>>>(hbuf, W2, 2048, 1024, 64, gpart);
  k_reduce_ep<<<256, 256, 0, stream>>>(gpart, 32, 64 * 1024, 1024, b2, nullptr, 2, qbuf, nullptr, nullptr);

  // P5/P6: u = (q @ A) * ent_sum           [64,1024], split 16
  k_gemm64<<<dim3(16, 16), 256, 0, stream>>>(qbuf, A, 1024, 1024, 64, gpart);
  k_reduce_ep<<<256, 256, 0, stream>>>(gpart, 16, 64 * 1024, 1024, entsum, nullptr, 3, ubuf, nullptr, nullptr);

  // P7/P8: z = q + u @ H (-> bf16 hi/lo)   [64,1024], split 16
  k_gemm64<<<dim3(16, 16), 256, 0, stream>>>(ubuf, H, 1024, 1024, 64, gpart);
  k_reduce_ep<<<256, 256, 0, stream>>>(gpart, 16, 64 * 1024, 1024, nullptr, qbuf, 4, nullptr, zhi16, zlo16);

  // P9: logits = z @ Ws + bs               [64,V], split-bf16 MFMA, dual double-buffer
  k_gemm_big<<<786, 256, 0, stream>>>(zhi16, zlo16, Ws, bs, logits);

  // P10/P11: softmax two-pass, 256 blocks each
  k_softmax1<<<256, 256, 0, stream>>>(logits, stats);
  k_softmax2<<<256, 256, 0, stream>>>(logits, stats, out);

  (void)in_sizes; (void)n_in; (void)out_size; (void)ws_size;
}

// Round 7
// 345.008 us; speedup vs baseline: 1.2361x; 1.2361x over previous
//
#include <hip/hip_runtime.h>
#include <stdint.h>

#define V_ 50257
#define D_ 1024
#define F_ 2048
#define B_ 64
#define E_ 512
#define ROWS_ (B_*E_)

typedef __attribute__((ext_vector_type(8))) short bf16x8;
typedef __attribute__((ext_vector_type(4))) float f32x4;

__device__ __forceinline__ unsigned rne1(float a) {
  unsigned u = __float_as_uint(a);
  return (u + 0x7FFFu + ((u >> 16) & 1u)) >> 16;
}

__device__ __forceinline__ float waveMax(float v) {
#pragma unroll
  for (int o = 32; o > 0; o >>= 1) v = fmaxf(v, __shfl_xor(v, o, 64));
  return v;
}
__device__ __forceinline__ float waveSum(float v) {
#pragma unroll
  for (int o = 32; o > 0; o >>= 1) v += __shfl_xor(v, o, 64);
  return v;
}

// ---------------- device bodies ----------------

__device__ __forceinline__ void ent_partial_body(int bid, const float* __restrict__ eh,
                                                 const void* __restrict__ mask,
                                                 float* __restrict__ part) {
  __shared__ int s_mode;
  const int tid = threadIdx.x;
  const uint32_t* mu = (const uint32_t*)mask;
  int f = 0;
  for (int i = tid; i < (ROWS_ / 4); i += 256) {
    uint32_t u = mu[i];
    if (u == 0x3F800000u) f |= 2;
    else if (u & 0xFFFFFF00u) f |= 1;
  }
  if (tid == 0) s_mode = 0;
  __syncthreads();
  if (f) atomicOr(&s_mode, f);
  __syncthreads();
  const int sm = s_mode;
  const int mode = (sm & 1) ? 1 : ((sm & 2) ? 2 : 0);

  float4 acc = make_float4(0.f, 0.f, 0.f, 0.f);
  const float4* eh4 = (const float4*)eh;
  for (int row = bid; row < ROWS_; row += 512) {
    bool on;
    if (mode == 1)      on = ((const unsigned char*)mask)[row] != 0;
    else if (mode == 2) on = ((const float*)mask)[row] != 0.f;
    else                on = ((const int*)mask)[row] != 0;
    if (on) {
      float4 v = eh4[(size_t)row * (D_ / 4) + tid];
      acc.x += v.x; acc.y += v.y; acc.z += v.z; acc.w += v.w;
    }
  }
  ((float4*)part)[(size_t)bid * (D_ / 4) + tid] = acc;
}

__device__ __forceinline__ void ent_reduce_body(int bid, const float* __restrict__ part,
                                                float* __restrict__ entsum) {
  int d = bid * 256 + threadIdx.x;
  float s0 = 0.f, s1 = 0.f, s2 = 0.f, s3 = 0.f;
  for (int i = 0; i < 512; i += 4) {
    s0 += part[(size_t)(i    ) * D_ + d];
    s1 += part[(size_t)(i + 1) * D_ + d];
    s2 += part[(size_t)(i + 2) * D_ + d];
    s3 += part[(size_t)(i + 3) * D_ + d];
  }
  entsum[d] = (s0 + s1) + (s2 + s3);
}

__device__ __forceinline__ void gemm64_body(int bx, int by, const float* __restrict__ X,
                                            const int* __restrict__ gatherIdx,
                                            const float* __restrict__ emb,
                                            const float* __restrict__ W,
                                            int K, int N, int KB, float* __restrict__ part) {
  const int l  = threadIdx.x & 63;
  const int rg = __builtin_amdgcn_readfirstlane((int)(threadIdx.x >> 6));
  const int c  = bx * 64 + l;
  const int k0 = by * KB;
  const int m0 = rg * 16;

  const float* Xp = gatherIdx ? emb : X;
  int rb[16];
#pragma unroll
  for (int r = 0; r < 16; ++r) {
    int m = m0 + r;
    rb[r] = gatherIdx ? gatherIdx[m] * K : m * K;
  }

  float acc[16];
#pragma unroll
  for (int r = 0; r < 16; ++r) acc[r] = 0.f;

  for (int k = k0; k < k0 + KB; k += 8) {
    float wv[8];
#pragma unroll
    for (int j = 0; j < 8; ++j) wv[j] = W[(size_t)(k + j) * N + c];
#pragma unroll
    for (int r = 0; r < 16; ++r) {
      float4 x0 = *(const float4*)&Xp[rb[r] + k];
      float4 x1 = *(const float4*)&Xp[rb[r] + k + 4];
      acc[r] = fmaf(x0.x, wv[0], acc[r]);
      acc[r] = fmaf(x0.y, wv[1], acc[r]);
      acc[r] = fmaf(x0.z, wv[2], acc[r]);
      acc[r] = fmaf(x0.w, wv[3], acc[r]);
      acc[r] = fmaf(x1.x, wv[4], acc[r]);
      acc[r] = fmaf(x1.y, wv[5], acc[r]);
      acc[r] = fmaf(x1.z, wv[6], acc[r]);
      acc[r] = fmaf(x1.w, wv[7], acc[r]);
    }
  }
  size_t base = (size_t)by * ((size_t)64 * N);
#pragma unroll
  for (int r = 0; r < 16; ++r) part[base + (size_t)(m0 + r) * N + c] = acc[r];
}

__device__ __forceinline__ void reduce_ep_body(int bid, const float* __restrict__ part,
                                               int nsplit, int MN, int N,
                                               const float* __restrict__ vecB,
                                               const float* __restrict__ addend,
                                               int mode, float* __restrict__ dst,
                                               unsigned short* __restrict__ dhi,
                                               unsigned short* __restrict__ dlo) {
  int idx = bid * 256 + threadIdx.x;
  if (idx >= MN) return;
  float s = 0.f;
  for (int i = 0; i < nsplit; ++i) s += part[(size_t)i * MN + idx];
  int c = idx & (N - 1);
  if (mode == 1)      { s += vecB[c]; s = s > 0.f ? s : 0.f; dst[idx] = s; }
  else if (mode == 2) { s += vecB[c]; dst[idx] = s; }
  else if (mode == 3) { s *= vecB[c]; dst[idx] = s; }
  else {
    s += addend[idx];
    unsigned hi = rne1(s);
    float hif = __uint_as_float(hi << 16);
    dhi[idx] = (unsigned short)hi;
    dlo[idx] = (unsigned short)rne1(s - hif);
  }
}

// ---------------- fused phase kernels ----------------
__global__ void k_p1(const float* __restrict__ eh, const void* __restrict__ mask,
                     float* __restrict__ entpart, const int* __restrict__ ques,
                     const float* __restrict__ emb, const float* __restrict__ W1,
                     float* __restrict__ gpart) {
  int bid = blockIdx.x;
  if (bid < 512) ent_partial_body(bid, eh, mask, entpart);
  else {
    int b2 = bid - 512;
    gemm64_body(b2 & 31, b2 >> 5, nullptr, ques, emb, W1, 1024, 2048, 64, gpart);
  }
}

__global__ void k_p2(const float* __restrict__ entpart, float* __restrict__ entsum,
                     const float* __restrict__ gpart, const float* __restrict__ b1,
                     float* __restrict__ hbuf) {
  int bid = blockIdx.x;
  if (bid < 4) ent_reduce_body(bid, entpart, entsum);
  else reduce_ep_body(bid - 4, gpart, 16, 64 * 2048, 2048, b1, nullptr, 1, hbuf, nullptr, nullptr);
}

__global__ void k_gemm64(const float* __restrict__ X, const float* __restrict__ W,
                         int K, int N, int KB, float* __restrict__ part) {
  gemm64_body(blockIdx.x, blockIdx.y, X, nullptr, nullptr, W, K, N, KB, part);
}

__global__ void k_reduce_ep(const float* __restrict__ part, int nsplit, int MN, int N,
                            const float* __restrict__ vecB, const float* __restrict__ addend,
                            int mode, float* __restrict__ dst,
                            unsigned short* __restrict__ dhi, unsigned short* __restrict__ dlo) {
  reduce_ep_body(blockIdx.x, part, nsplit, MN, N, vecB, addend, mode, dst, dhi, dlo);
}

// ---------------- big GEMM: logits = Z[64,1024] @ Ws[1024,V] + bs, split-bf16 MFMA -------
// 4 waves/block; wave w owns 16 cols, all 64 rows, full K. 2x-unrolled k-loop with named
// A/B buffer sets for BOTH streams (z frags + Ws batch). Compute-X depends only on X-bufs
// issued one full phase earlier -> compiler waitcnt is vmcnt(16): the other phase's 16
// loads stay in flight across every compute phase.
// launch_bounds(256,3): VGPR cap ~170. The pipeline needs ~135 VGPRs; round-6's (256,4)
// cap of 128 made the compiler spill the entire pipeline to scratch (WRITE_SIZE 92 MB).
__global__ __launch_bounds__(256, 3) void k_gemm_big(const unsigned short* __restrict__ zhi,
                                                     const unsigned short* __restrict__ zlo,
                                                     const float* __restrict__ Ws,
                                                     const float* __restrict__ bs,
                                                     float* __restrict__ logits) {
  const int l   = threadIdx.x & 63;
  const int w   = threadIdx.x >> 6;
  const int col = l & 15;
  const int g   = l >> 4;            // k-chunk g*8..g*8+7
  const int c   = blockIdx.x * 64 + w * 16 + col;
  const int cc  = c < V_ ? c : V_ - 1;

  unsigned woff[8];
#pragma unroll
  for (int j = 0; j < 8; ++j) woff[j] = (unsigned)((g * 8 + j) * V_ + cc);
  unsigned aoff[4];
#pragma unroll
  for (int m = 0; m < 4; ++m) aoff[m] = (unsigned)((m * 16 + col) * D_ + g * 8);

  f32x4 zero = {0.f, 0.f, 0.f, 0.f};
  f32x4 acc[4];
#pragma unroll
  for (int m = 0; m < 4; ++m) acc[m] = zero;

  bf16x8 ahA[4], alA[4], ahB[4], alB[4];
  float fA[8], fB[8];

  // prologue: phase-A data for k0=0 (z first, then Ws)
#pragma unroll
  for (int m = 0; m < 4; ++m) {
    ahA[m] = *(const bf16x8*)(zhi + aoff[m]);
    alA[m] = *(const bf16x8*)(zlo + aoff[m]);
  }
#pragma unroll
  for (int j = 0; j < 8; ++j) fA[j] = Ws[woff[j]];
#pragma unroll
  for (int j = 0; j < 8; ++j) fB[j] = 0.f;

  for (int k0 = 0; k0 < D_; k0 += 64) {
    // issue phase-B loads (k0+32): z first, then Ws
    {
      const unsigned short* zh = zhi + k0 + 32;
      const unsigned short* zl = zlo + k0 + 32;
#pragma unroll
      for (int m = 0; m < 4; ++m) {
        ahB[m] = *(const bf16x8*)(zh + aoff[m]);
        alB[m] = *(const bf16x8*)(zl + aoff[m]);
      }
      const float* wn = Ws + (size_t)(k0 + 32) * V_;
#pragma unroll
      for (int j = 0; j < 8; ++j) fB[j] = wn[woff[j]];
    }

    // compute phase A (k0)
    {
      union { bf16x8 v; unsigned u[4]; } bh, bl;
#pragma unroll
      for (int j = 0; j < 4; ++j) {
        unsigned h0 = rne1(fA[2 * j]);
        unsigned h1 = rne1(fA[2 * j + 1]);
        float h0f = __uint_as_float(h0 << 16);
        float h1f = __uint_as_float(h1 << 16);
        bh.u[j] = h0 | (h1 << 16);
        bl.u[j] = rne1(fA[2 * j] - h0f) | (rne1(fA[2 * j + 1] - h1f) << 16);
      }
#pragma unroll
      for (int m = 0; m < 4; ++m) acc[m] = __builtin_amdgcn_mfma_f32_16x16x32_bf16(ahA[m], bh.v, acc[m], 0, 0, 0);
#pragma unroll
      for (int m = 0; m < 4; ++m) acc[m] = __builtin_amdgcn_mfma_f32_16x16x32_bf16(ahA[m], bl.v, acc[m], 0, 0, 0);
#pragma unroll
      for (int m = 0; m < 4; ++m) acc[m] = __builtin_amdgcn_mfma_f32_16x16x32_bf16(alA[m], bh.v, acc[m], 0, 0, 0);
    }

    // issue phase-A loads (k0+64): z first, then Ws
    if (k0 + 64 < D_) {
      const unsigned short* zh = zhi + k0 + 64;
      const unsigned short* zl = zlo + k0 + 64;
#pragma unroll
      for (int m = 0; m < 4; ++m) {
        ahA[m] = *(const bf16x8*)(zh + aoff[m]);
        alA[m] = *(const bf16x8*)(zl + aoff[m]);
      }
      const float* wn = Ws + (size_t)(k0 + 64) * V_;
#pragma unroll
      for (int j = 0; j < 8; ++j) fA[j] = wn[woff[j]];
    }

    // compute phase B (k0+32)
    {
      union { bf16x8 v; unsigned u[4]; } bh, bl;
#pragma unroll
      for (int j = 0; j < 4; ++j) {
        unsigned h0 = rne1(fB[2 * j]);
        unsigned h1 = rne1(fB[2 * j + 1]);
        float h0f = __uint_as_float(h0 << 16);
        float h1f = __uint_as_float(h1 << 16);
        bh.u[j] = h0 | (h1 << 16);
        bl.u[j] = rne1(fB[2 * j] - h0f) | (rne1(fB[2 * j + 1] - h1f) << 16);
      }
#pragma unroll
      for (int m = 0; m < 4; ++m) acc[m] = __builtin_amdgcn_mfma_f32_16x16x32_bf16(ahB[m], bh.v, acc[m], 0, 0, 0);
#pragma unroll
      for (int m = 0; m < 4; ++m) acc[m] = __builtin_amdgcn_mfma_f32_16x16x32_bf16(ahB[m], bl.v, acc[m], 0, 0, 0);
#pragma unroll
      for (int m = 0; m < 4; ++m) acc[m] = __builtin_amdgcn_mfma_f32_16x16x32_bf16(alB[m], bh.v, acc[m], 0, 0, 0);
    }
  }

  if (c < V_) {
    float bias = bs[c];
#pragma unroll
    for (int m = 0; m < 4; ++m) {
#pragma unroll
      for (int i = 0; i < 4; ++i)
        logits[(size_t)(m * 16 + g * 4 + i) * V_ + c] = acc[m][i] + bias;
    }
  }
}

// ---------------- softmax over rows of logits [64, V], two-pass 256-block ----------------
#define SM_CHUNK 12565  // 4 * 12565 >= V_

__global__ void k_softmax1(const float* __restrict__ logits, float2* __restrict__ stats) {
  __shared__ float smx[4], ssum[4];
  const int r = blockIdx.x >> 2, q = blockIdx.x & 3;
  const int beg = q * SM_CHUNK;
  const int end = (beg + SM_CHUNK < V_) ? beg + SM_CHUNK : V_;
  const float* row = logits + (size_t)r * V_;

  float mx = -3.4e38f;
  for (int i = beg + threadIdx.x; i < end; i += 256) mx = fmaxf(mx, row[i]);
  mx = waveMax(mx);
  if ((threadIdx.x & 63) == 0) smx[threadIdx.x >> 6] = mx;
  __syncthreads();
  mx = fmaxf(fmaxf(smx[0], smx[1]), fmaxf(smx[2], smx[3]));

  float s = 0.f;
  for (int i = beg + threadIdx.x; i < end; i += 256) s += __expf(row[i] - mx);
  s = waveSum(s);
  if ((threadIdx.x & 63) == 0) ssum[threadIdx.x >> 6] = s;
  __syncthreads();
  s = (ssum[0] + ssum[1]) + (ssum[2] + ssum[3]);

  if (threadIdx.x == 0) stats[blockIdx.x] = make_float2(mx, s);
}

__global__ void k_softmax2(const float* __restrict__ logits, const float2* __restrict__ stats,
                           float* __restrict__ out) {
  const int r = blockIdx.x >> 2, q = blockIdx.x & 3;
  float2 s0 = stats[r * 4 + 0], s1 = stats[r * 4 + 1];
  float2 s2 = stats[r * 4 + 2], s3 = stats[r * 4 + 3];
  float M = fmaxf(fmaxf(s0.x, s1.x), fmaxf(s2.x, s3.x));
  float S = s0.y * __expf(s0.x - M) + s1.y * __expf(s1.x - M)
          + s2.y * __expf(s2.x - M) + s3.y * __expf(s3.x - M);
  float inv = 1.f / S;
  const int beg = q * SM_CHUNK;
  const int end = (beg + SM_CHUNK < V_) ? beg + SM_CHUNK : V_;
  const float* row = logits + (size_t)r * V_;
  float* orow = out + (size_t)r * V_;
  for (int i = beg + threadIdx.x; i < end; i += 256) orow[i] = __expf(row[i] - M) * inv;
}

// ---------------- launch ----------------
extern "C" void kernel_launch(void* const* d_in, const int* in_sizes, int n_in,
                              void* d_out, int out_size, void* d_ws, size_t ws_size,
                              hipStream_t stream) {
  const float* eh   = (const float*)d_in[0];
  const int*   ques = (const int*)d_in[1];
  const void*  mask = d_in[2];
  const float* emb  = (const float*)d_in[3];
  const float* W1   = (const float*)d_in[4];
  const float* b1   = (const float*)d_in[5];
  const float* W2   = (const float*)d_in[6];
  const float* b2   = (const float*)d_in[7];
  const float* A    = (const float*)d_in[8];
  const float* H    = (const float*)d_in[9];
  const float* Ws   = (const float*)d_in[10];
  const float* bs   = (const float*)d_in[11];
  float* out = (float*)d_out;
  char* ws = (char*)d_ws;

  // ws layout (bytes). gpart aliases logits (temporally disjoint).
  float*          logits  = (float*)(ws + 0);           // 64*50257*4 = 12,865,792
  float*          gpart   = (float*)(ws + 0);           // max 8,388,608 (aliased)
  float*          entpart = (float*)(ws + 12866048);    // 2,097,152
  float*          entsum  = (float*)(ws + 14963200);    // 4,096
  float*          hbuf    = (float*)(ws + 14967296);    // 524,288
  float*          qbuf    = (float*)(ws + 15491584);    // 262,144
  float*          ubuf    = (float*)(ws + 15753728);    // 262,144
  unsigned short* zhi16   = (unsigned short*)(ws + 16015872);  // 131,072
  unsigned short* zlo16   = (unsigned short*)(ws + 16146944);  // 131,072
  float2*         stats   = (float2*)(ws + 16278016);   // 2,048

  // P1: ent_partial (512 blocks) || h-gemm partials (512 blocks)
  k_p1<<<1024, 256, 0, stream>>>(eh, mask, entpart, ques, emb, W1, gpart);
  // P2: ent_reduce (4) || h = relu(.+b1) (512)
  k_p2<<<516, 256, 0, stream>>>(entpart, entsum, gpart, b1, hbuf);

  // P3/P4: q = h @ W2 + b2                 [64,1024], K=2048, split 32
  k_gemm64<<<dim3(16, 32), 256, 0, stream>>>(hbuf, W2, 2048, 1024, 64, gpart);
  k_reduce_ep<<<256, 256, 0, stream>>>(gpart, 32, 64 * 1024, 1024, b2, nullptr, 2, qbuf, nullptr, nullptr);

  // P5/P6: u = (q @ A) * ent_sum           [64,1024], split 16
  k_gemm64<<<dim3(16, 16), 256, 0, stream>>>(qbuf, A, 1024, 1024, 64, gpart);
  k_reduce_ep<<<256, 256, 0, stream>>>(gpart, 16, 64 * 1024, 1024, entsum, nullptr, 3, ubuf, nullptr, nullptr);

  // P7/P8: z = q + u @ H (-> bf16 hi/lo)   [64,1024], split 16
  k_gemm64<<<dim3(16, 16), 256, 0, stream>>>(ubuf, H, 1024, 1024, 64, gpart);
  k_reduce_ep<<<256, 256, 0, stream>>>(gpart, 16, 64 * 1024, 1024, nullptr, qbuf, 4, nullptr, zhi16, zlo16);

  // P9: logits = z @ Ws + bs               [64,V], split-bf16 MFMA, dual double-buffer
  k_gemm_big<<<786, 256, 0, stream>>>(zhi16, zlo16, Ws, bs, logits);

  // P10/P11: softmax two-pass, 256 blocks each
  k_softmax1<<<256, 256, 0, stream>>>(logits, stats);
  k_softmax2<<<256, 256, 0, stream>>>(logits, stats, out);

  (void)in_sizes; (void)n_in; (void)out_size; (void)ws_size;
}

// Round 8
// 323.058 us; speedup vs baseline: 1.3201x; 1.0679x over previous
//
#include <hip/hip_runtime.h>
#include <stdint.h>

#define V_ 50257
#define D_ 1024
#define F_ 2048
#define B_ 64
#define E_ 512
#define ROWS_ (B_*E_)

typedef __attribute__((ext_vector_type(8))) short bf16x8;
typedef __attribute__((ext_vector_type(4))) float f32x4;

__device__ __forceinline__ unsigned rne1(float a) {
  unsigned u = __float_as_uint(a);
  return (u + 0x7FFFu + ((u >> 16) & 1u)) >> 16;
}

__device__ __forceinline__ float waveMax(float v) {
#pragma unroll
  for (int o = 32; o > 0; o >>= 1) v = fmaxf(v, __shfl_xor(v, o, 64));
  return v;
}
__device__ __forceinline__ float waveSum(float v) {
#pragma unroll
  for (int o = 32; o > 0; o >>= 1) v += __shfl_xor(v, o, 64);
  return v;
}

// ---------------- device bodies ----------------

__device__ __forceinline__ void ent_partial_body(int bid, const float* __restrict__ eh,
                                                 const void* __restrict__ mask,
                                                 float* __restrict__ part) {
  __shared__ int s_mode;
  const int tid = threadIdx.x;
  const uint32_t* mu = (const uint32_t*)mask;
  int f = 0;
  for (int i = tid; i < (ROWS_ / 4); i += 256) {
    uint32_t u = mu[i];
    if (u == 0x3F800000u) f |= 2;
    else if (u & 0xFFFFFF00u) f |= 1;
  }
  if (tid == 0) s_mode = 0;
  __syncthreads();
  if (f) atomicOr(&s_mode, f);
  __syncthreads();
  const int sm = s_mode;
  const int mode = (sm & 1) ? 1 : ((sm & 2) ? 2 : 0);

  float4 acc = make_float4(0.f, 0.f, 0.f, 0.f);
  const float4* eh4 = (const float4*)eh;
  for (int row = bid; row < ROWS_; row += 512) {
    bool on;
    if (mode == 1)      on = ((const unsigned char*)mask)[row] != 0;
    else if (mode == 2) on = ((const float*)mask)[row] != 0.f;
    else                on = ((const int*)mask)[row] != 0;
    if (on) {
      float4 v = eh4[(size_t)row * (D_ / 4) + tid];
      acc.x += v.x; acc.y += v.y; acc.z += v.z; acc.w += v.w;
    }
  }
  ((float4*)part)[(size_t)bid * (D_ / 4) + tid] = acc;
}

__device__ __forceinline__ void ent_reduce_body(int bid, const float* __restrict__ part,
                                                float* __restrict__ entsum) {
  int d = bid * 256 + threadIdx.x;
  float s0 = 0.f, s1 = 0.f, s2 = 0.f, s3 = 0.f;
  for (int i = 0; i < 512; i += 4) {
    s0 += part[(size_t)(i    ) * D_ + d];
    s1 += part[(size_t)(i + 1) * D_ + d];
    s2 += part[(size_t)(i + 2) * D_ + d];
    s3 += part[(size_t)(i + 3) * D_ + d];
  }
  entsum[d] = (s0 + s1) + (s2 + s3);
}

__device__ __forceinline__ void gemm64_body(int bx, int by, const float* __restrict__ X,
                                            const int* __restrict__ gatherIdx,
                                            const float* __restrict__ emb,
                                            const float* __restrict__ W,
                                            int K, int N, int KB, float* __restrict__ part) {
  const int l  = threadIdx.x & 63;
  const int rg = __builtin_amdgcn_readfirstlane((int)(threadIdx.x >> 6));
  const int c  = bx * 64 + l;
  const int k0 = by * KB;
  const int m0 = rg * 16;

  const float* Xp = gatherIdx ? emb : X;
  int rb[16];
#pragma unroll
  for (int r = 0; r < 16; ++r) {
    int m = m0 + r;
    rb[r] = gatherIdx ? gatherIdx[m] * K : m * K;
  }

  float acc[16];
#pragma unroll
  for (int r = 0; r < 16; ++r) acc[r] = 0.f;

  for (int k = k0; k < k0 + KB; k += 8) {
    float wv[8];
#pragma unroll
    for (int j = 0; j < 8; ++j) wv[j] = W[(size_t)(k + j) * N + c];
#pragma unroll
    for (int r = 0; r < 16; ++r) {
      float4 x0 = *(const float4*)&Xp[rb[r] + k];
      float4 x1 = *(const float4*)&Xp[rb[r] + k + 4];
      acc[r] = fmaf(x0.x, wv[0], acc[r]);
      acc[r] = fmaf(x0.y, wv[1], acc[r]);
      acc[r] = fmaf(x0.z, wv[2], acc[r]);
      acc[r] = fmaf(x0.w, wv[3], acc[r]);
      acc[r] = fmaf(x1.x, wv[4], acc[r]);
      acc[r] = fmaf(x1.y, wv[5], acc[r]);
      acc[r] = fmaf(x1.z, wv[6], acc[r]);
      acc[r] = fmaf(x1.w, wv[7], acc[r]);
    }
  }
  size_t base = (size_t)by * ((size_t)64 * N);
#pragma unroll
  for (int r = 0; r < 16; ++r) part[base + (size_t)(m0 + r) * N + c] = acc[r];
}

__device__ __forceinline__ void reduce_ep_body(int bid, const float* __restrict__ part,
                                               int nsplit, int MN, int N,
                                               const float* __restrict__ vecB,
                                               const float* __restrict__ addend,
                                               int mode, float* __restrict__ dst,
                                               unsigned short* __restrict__ dhi,
                                               unsigned short* __restrict__ dlo) {
  int idx = bid * 256 + threadIdx.x;
  if (idx >= MN) return;
  float s = 0.f;
  for (int i = 0; i < nsplit; ++i) s += part[(size_t)i * MN + idx];
  int c = idx & (N - 1);
  if (mode == 1)      { s += vecB[c]; s = s > 0.f ? s : 0.f; dst[idx] = s; }
  else if (mode == 2) { s += vecB[c]; dst[idx] = s; }
  else if (mode == 3) { s *= vecB[c]; dst[idx] = s; }
  else {
    s += addend[idx];
    unsigned hi = rne1(s);
    float hif = __uint_as_float(hi << 16);
    dhi[idx] = (unsigned short)hi;
    dlo[idx] = (unsigned short)rne1(s - hif);
  }
}

// ---------------- fused phase kernels ----------------
__global__ void k_p1(const float* __restrict__ eh, const void* __restrict__ mask,
                     float* __restrict__ entpart, const int* __restrict__ ques,
                     const float* __restrict__ emb, const float* __restrict__ W1,
                     float* __restrict__ gpart) {
  int bid = blockIdx.x;
  if (bid < 512) ent_partial_body(bid, eh, mask, entpart);
  else {
    int b2 = bid - 512;
    gemm64_body(b2 & 31, b2 >> 5, nullptr, ques, emb, W1, 1024, 2048, 64, gpart);
  }
}

__global__ void k_p2(const float* __restrict__ entpart, float* __restrict__ entsum,
                     const float* __restrict__ gpart, const float* __restrict__ b1,
                     float* __restrict__ hbuf) {
  int bid = blockIdx.x;
  if (bid < 4) ent_reduce_body(bid, entpart, entsum);
  else reduce_ep_body(bid - 4, gpart, 16, 64 * 2048, 2048, b1, nullptr, 1, hbuf, nullptr, nullptr);
}

__global__ void k_gemm64(const float* __restrict__ X, const float* __restrict__ W,
                         int K, int N, int KB, float* __restrict__ part) {
  gemm64_body(blockIdx.x, blockIdx.y, X, nullptr, nullptr, W, K, N, KB, part);
}

__global__ void k_reduce_ep(const float* __restrict__ part, int nsplit, int MN, int N,
                            const float* __restrict__ vecB, const float* __restrict__ addend,
                            int mode, float* __restrict__ dst,
                            unsigned short* __restrict__ dhi, unsigned short* __restrict__ dlo) {
  reduce_ep_body(blockIdx.x, part, nsplit, MN, N, vecB, addend, mode, dst, dhi, dlo);
}

// ---------------- big GEMM: logits = Z[64,1024] @ Ws[1024,V] + bs, split-bf16 MFMA -------
// LDS-staged Ws stream (m97 pattern): double-buffered 32x64 f32 tile (8 KB) staged via
// __builtin_amdgcn_global_load_lds size=4 (V odd -> rows mutually misaligned, 16B illegal).
// DMA loads hold no VGPRs -> the compiler cannot sink them (rounds 5-7 failure mode).
// Per k-step: z-frag loads (issued FIRST so their vmcnt wait leaves staging in flight),
// stage next tile into lds[buf^1], compute from lds[buf], one __syncthreads (its
// vmcnt/lgkm drain makes the next buffer ready and retires this buffer's reads).
__global__ __launch_bounds__(256) void k_gemm_big(const unsigned short* __restrict__ zhi,
                                                  const unsigned short* __restrict__ zlo,
                                                  const float* __restrict__ Ws,
                                                  const float* __restrict__ bs,
                                                  float* __restrict__ logits) {
  __shared__ float lds[2][32 * 64];
  const int t   = threadIdx.x;
  const int l   = t & 63;
  const int w   = t >> 6;
  const int col = l & 15;
  const int g   = l >> 4;            // k-chunk g*8..g*8+7
  const int c0  = blockIdx.x * 64;
  const int c   = c0 + w * 16 + col;

  // staging source column for this lane (clamped for the tail block)
  int scol = c0 + l;
  if (scol > V_ - 1) scol = V_ - 1;

  unsigned aoff[4];
#pragma unroll
  for (int m = 0; m < 4; ++m) aoff[m] = (unsigned)((m * 16 + col) * D_ + g * 8);

  f32x4 acc[4];
#pragma unroll
  for (int m = 0; m < 4; ++m) acc[m] = (f32x4){0.f, 0.f, 0.f, 0.f};

  // prologue: stage tile 0 (rows 0..31). wave w, round i stages row i*4+w:
  // 64 lanes write lds[0][r*64 + lane] <- Ws[r][scol] (256 B coalesced per round).
#pragma unroll
  for (int i = 0; i < 8; ++i) {
    const int r = i * 4 + w;
    __builtin_amdgcn_global_load_lds(
        (const __attribute__((address_space(1))) void*)(Ws + (size_t)r * V_ + scol),
        (__attribute__((address_space(3))) void*)&lds[0][r * 64],
        4, 0, 0);
  }
  __syncthreads();

  for (int it = 0; it < 32; ++it) {
    const int k0 = it * 32;
    const int buf = it & 1;

    // A-fragments (z, L2-resident) — issued BEFORE the stage so waiting for them
    // is vmcnt(8), leaving the staging DMA in flight under the compute.
    bf16x8 ah[4], al[4];
#pragma unroll
    for (int m = 0; m < 4; ++m) {
      ah[m] = *(const bf16x8*)(zhi + aoff[m] + k0);
      al[m] = *(const bf16x8*)(zlo + aoff[m] + k0);
    }

    if (it + 1 < 32) {
      const float* wbase = Ws + (size_t)(k0 + 32) * V_ + scol;
#pragma unroll
      for (int i = 0; i < 8; ++i) {
        const int r = i * 4 + w;
        __builtin_amdgcn_global_load_lds(
            (const __attribute__((address_space(1))) void*)(wbase + (size_t)r * V_),
            (__attribute__((address_space(3))) void*)&lds[buf ^ 1][r * 64],
            4, 0, 0);
      }
    }

    // B from LDS (wave w reads its 16-col slice), convert to bf16 hi/lo, MFMA.
    float f[8];
#pragma unroll
    for (int j = 0; j < 8; ++j) f[j] = lds[buf][(g * 8 + j) * 64 + w * 16 + col];

    union { bf16x8 v; unsigned u[4]; } bh, bl;
#pragma unroll
    for (int j = 0; j < 4; ++j) {
      unsigned h0 = rne1(f[2 * j]);
      unsigned h1 = rne1(f[2 * j + 1]);
      float h0f = __uint_as_float(h0 << 16);
      float h1f = __uint_as_float(h1 << 16);
      bh.u[j] = h0 | (h1 << 16);
      bl.u[j] = rne1(f[2 * j] - h0f) | (rne1(f[2 * j + 1] - h1f) << 16);
    }
#pragma unroll
    for (int m = 0; m < 4; ++m) acc[m] = __builtin_amdgcn_mfma_f32_16x16x32_bf16(ah[m], bh.v, acc[m], 0, 0, 0);
#pragma unroll
    for (int m = 0; m < 4; ++m) acc[m] = __builtin_amdgcn_mfma_f32_16x16x32_bf16(ah[m], bl.v, acc[m], 0, 0, 0);
#pragma unroll
    for (int m = 0; m < 4; ++m) acc[m] = __builtin_amdgcn_mfma_f32_16x16x32_bf16(al[m], bh.v, acc[m], 0, 0, 0);

    __syncthreads();
  }

  if (c < V_) {
    float bias = bs[c];
#pragma unroll
    for (int m = 0; m < 4; ++m) {
#pragma unroll
      for (int i = 0; i < 4; ++i)
        logits[(size_t)(m * 16 + g * 4 + i) * V_ + c] = acc[m][i] + bias;
    }
  }
}

// ---------------- softmax over rows of logits [64, V], two-pass 256-block ----------------
#define SM_CHUNK 12565  // 4 * 12565 >= V_

__global__ void k_softmax1(const float* __restrict__ logits, float2* __restrict__ stats) {
  __shared__ float smx[4], ssum[4];
  const int r = blockIdx.x >> 2, q = blockIdx.x & 3;
  const int beg = q * SM_CHUNK;
  const int end = (beg + SM_CHUNK < V_) ? beg + SM_CHUNK : V_;
  const float* row = logits + (size_t)r * V_;

  float mx = -3.4e38f;
  for (int i = beg + threadIdx.x; i < end; i += 256) mx = fmaxf(mx, row[i]);
  mx = waveMax(mx);
  if ((threadIdx.x & 63) == 0) smx[threadIdx.x >> 6] = mx;
  __syncthreads();
  mx = fmaxf(fmaxf(smx[0], smx[1]), fmaxf(smx[2], smx[3]));

  float s = 0.f;
  for (int i = beg + threadIdx.x; i < end; i += 256) s += __expf(row[i] - mx);
  s = waveSum(s);
  if ((threadIdx.x & 63) == 0) ssum[threadIdx.x >> 6] = s;
  __syncthreads();
  s = (ssum[0] + ssum[1]) + (ssum[2] + ssum[3]);

  if (threadIdx.x == 0) stats[blockIdx.x] = make_float2(mx, s);
}

__global__ void k_softmax2(const float* __restrict__ logits, const float2* __restrict__ stats,
                           float* __restrict__ out) {
  const int r = blockIdx.x >> 2, q = blockIdx.x & 3;
  float2 s0 = stats[r * 4 + 0], s1 = stats[r * 4 + 1];
  float2 s2 = stats[r * 4 + 2], s3 = stats[r * 4 + 3];
  float M = fmaxf(fmaxf(s0.x, s1.x), fmaxf(s2.x, s3.x));
  float S = s0.y * __expf(s0.x - M) + s1.y * __expf(s1.x - M)
          + s2.y * __expf(s2.x - M) + s3.y * __expf(s3.x - M);
  float inv = 1.f / S;
  const int beg = q * SM_CHUNK;
  const int end = (beg + SM_CHUNK < V_) ? beg + SM_CHUNK : V_;
  const float* row = logits + (size_t)r * V_;
  float* orow = out + (size_t)r * V_;
  for (int i = beg + threadIdx.x; i < end; i += 256) orow[i] = __expf(row[i] - M) * inv;
}

// ---------------- launch ----------------
extern "C" void kernel_launch(void* const* d_in, const int* in_sizes, int n_in,
                              void* d_out, int out_size, void* d_ws, size_t ws_size,
                              hipStream_t stream) {
  const float* eh   = (const float*)d_in[0];
  const int*   ques = (const int*)d_in[1];
  const void*  mask = d_in[2];
  const float* emb  = (const float*)d_in[3];
  const float* W1   = (const float*)d_in[4];
  const float* b1   = (const float*)d_in[5];
  const float* W2   = (const float*)d_in[6];
  const float* b2   = (const float*)d_in[7];
  const float* A    = (const float*)d_in[8];
  const float* H    = (const float*)d_in[9];
  const float* Ws   = (const float*)d_in[10];
  const float* bs   = (const float*)d_in[11];
  float* out = (float*)d_out;
  char* ws = (char*)d_ws;

  // ws layout (bytes). gpart aliases logits (temporally disjoint).
  float*          logits  = (float*)(ws + 0);           // 64*50257*4 = 12,865,792
  float*          gpart   = (float*)(ws + 0);           // max 8,388,608 (aliased)
  float*          entpart = (float*)(ws + 12866048);    // 2,097,152
  float*          entsum  = (float*)(ws + 14963200);    // 4,096
  float*          hbuf    = (float*)(ws + 14967296);    // 524,288
  float*          qbuf    = (float*)(ws + 15491584);    // 262,144
  float*          ubuf    = (float*)(ws + 15753728);    // 262,144
  unsigned short* zhi16   = (unsigned short*)(ws + 16015872);  // 131,072
  unsigned short* zlo16   = (unsigned short*)(ws + 16146944);  // 131,072
  float2*         stats   = (float2*)(ws + 16278016);   // 2,048

  // P1: ent_partial (512 blocks) || h-gemm partials (512 blocks)
  k_p1<<<1024, 256, 0, stream>>>(eh, mask, entpart, ques, emb, W1, gpart);
  // P2: ent_reduce (4) || h = relu(.+b1) (512)
  k_p2<<<516, 256, 0, stream>>>(entpart, entsum, gpart, b1, hbuf);

  // P3/P4: q = h @ W2 + b2                 [64,1024], K=2048, split 32
  k_gemm64<<<dim3(16, 32), 256, 0, stream>>>(hbuf, W2, 2048, 1024, 64, gpart);
  k_reduce_ep<<<256, 256, 0, stream>>>(gpart, 32, 64 * 1024, 1024, b2, nullptr, 2, qbuf, nullptr, nullptr);

  // P5/P6: u = (q @ A) * ent_sum           [64,1024], split 16
  k_gemm64<<<dim3(16, 16), 256, 0, stream>>>(qbuf, A, 1024, 1024, 64, gpart);
  k_reduce_ep<<<256, 256, 0, stream>>>(gpart, 16, 64 * 1024, 1024, entsum, nullptr, 3, ubuf, nullptr, nullptr);

  // P7/P8: z = q + u @ H (-> bf16 hi/lo)   [64,1024], split 16
  k_gemm64<<<dim3(16, 16), 256, 0, stream>>>(ubuf, H, 1024, 1024, 64, gpart);
  k_reduce_ep<<<256, 256, 0, stream>>>(gpart, 16, 64 * 1024, 1024, nullptr, qbuf, 4, nullptr, zhi16, zlo16);

  // P9: logits = z @ Ws + bs               [64,V], split-bf16 MFMA, LDS-staged Ws
  k_gemm_big<<<786, 256, 0, stream>>>(zhi16, zlo16, Ws, bs, logits);

  // P10/P11: softmax two-pass, 256 blocks each
  k_softmax1<<<256, 256, 0, stream>>>(logits, stats);
  k_softmax2<<<256, 256, 0, stream>>>(logits, stats, out);

  (void)in_sizes; (void)n_in; (void)out_size; (void)ws_size;
}